// Round 1
// baseline (156.066 us; speedup 1.0000x reference)
//
#include <hip/hip_runtime.h>

#define BB 2
#define CC 64
#define HH 128
#define WW 128
#define NN (HH*WW)          // 16384 queries
#define MM ((HH/2)*(WW/2))  // 4096 keys
#define CK 8                // theta/phi channels
#define CV 32               // g channels
#define KS 8                // key split factor
#define KSEG (MM/KS)        // 512 keys per segment
#define QB (NN/256)         // 64 query blocks

typedef __attribute__((ext_vector_type(8))) short bf16x8;
typedef __attribute__((ext_vector_type(4))) float f32x4;
typedef unsigned int uint32;

__device__ __forceinline__ short f2bf(float f) {
    union { float f; unsigned u; } v; v.f = f;
    unsigned u = v.u + 0x7fffu + ((v.u >> 16) & 1u);   // RNE
    return (short)(u >> 16);
}

__device__ __forceinline__ uint32 pack2bf(float lo, float hi) {
    return (uint32)(unsigned short)f2bf(lo) | ((uint32)(unsigned short)f2bf(hi) << 16);
}

// ---------------------------------------------------------------------------
// Kernel 1: conv1x1 projections + 2x2 maxpool (pool AFTER projection).
// Block = 256 threads = image strip of 2 rows x 128 cols. Grid = (64, B).
// Outputs: Qb [B][N][8] bf16, Kb [B][M][8] bf16, Vt [B][32][M] bf16.
// ---------------------------------------------------------------------------
__global__ __launch_bounds__(256) void proj_kernel(
    const float* __restrict__ x, const float* __restrict__ wt,
    const float* __restrict__ wp, const float* __restrict__ wg,
    short* __restrict__ Qb, short* __restrict__ Kb, short* __restrict__ Vt)
{
    __shared__ float w_lds[48*64];       // [0:8)=theta, [8:16)=phi, [16:48)=g
    __shared__ float pg_lds[256][40];    // per source pixel: phi[8], g[32]
    int tid = threadIdx.x;
    for (int i = tid; i < 3072; i += 256) {
        float v;
        if (i < 512)       v = wt[i];
        else if (i < 1024) v = wp[i-512];
        else               v = wg[i-1024];
        w_lds[i] = v;
    }
    __syncthreads();

    int s = blockIdx.x;      // strip: image rows 2s, 2s+1
    int b = blockIdx.y;
    int r  = tid >> 7;       // 0..1 row within strip
    int wc = tid & 127;      // col
    int n = (2*s + r)*WW + wc;

    float xv[64];
    #pragma unroll
    for (int c = 0; c < 64; ++c) xv[c] = x[((b*CC + c) << 14) + n];

    // theta -> global directly (16B per pixel, coalesced)
    {
        float th[8];
        #pragma unroll
        for (int o = 0; o < 8; ++o) {
            float a = 0.f;
            #pragma unroll
            for (int c = 0; c < 64; ++c) a += w_lds[o*64 + c] * xv[c];
            th[o] = a;
        }
        uint4 val;
        val.x = pack2bf(th[0], th[1]); val.y = pack2bf(th[2], th[3]);
        val.z = pack2bf(th[4], th[5]); val.w = pack2bf(th[6], th[7]);
        ((uint4*)Qb)[b*NN + n] = val;
    }
    // phi, g -> LDS for pooling
    #pragma unroll
    for (int o = 0; o < 8; ++o) {
        float a = 0.f;
        #pragma unroll
        for (int c = 0; c < 64; ++c) a += w_lds[512 + o*64 + c] * xv[c];
        pg_lds[tid][o] = a;
    }
    #pragma unroll
    for (int o = 0; o < 32; ++o) {
        float a = 0.f;
        #pragma unroll
        for (int c = 0; c < 64; ++c) a += w_lds[1024 + o*64 + c] * xv[c];
        pg_lds[tid][8 + o] = a;
    }
    __syncthreads();

    if (tid < 64) {
        int w2 = tid;
        int t00 = 2*w2, t01 = t00 + 1, t10 = 128 + 2*w2, t11 = t10 + 1;
        int m = s*(WW/2) + w2;     // pooled index within batch
        float kf[8];
        #pragma unroll
        for (int o = 0; o < 8; ++o) {
            kf[o] = fmaxf(fmaxf(pg_lds[t00][o], pg_lds[t01][o]),
                          fmaxf(pg_lds[t10][o], pg_lds[t11][o]));
        }
        uint4 val;
        val.x = pack2bf(kf[0], kf[1]); val.y = pack2bf(kf[2], kf[3]);
        val.z = pack2bf(kf[4], kf[5]); val.w = pack2bf(kf[6], kf[7]);
        ((uint4*)Kb)[b*MM + m] = val;
        #pragma unroll
        for (int o = 0; o < 32; ++o) {
            float a = fmaxf(fmaxf(pg_lds[t00][8+o], pg_lds[t01][8+o]),
                            fmaxf(pg_lds[t10][8+o], pg_lds[t11][8+o]));
            Vt[(b*CV + o)*MM + m] = f2bf(a);
        }
    }
}

// ---------------------------------------------------------------------------
// Kernel 2: flash attention (no max-subtraction), MFMA bf16 16x16x32.
// Block = 256 = 4 waves; wave owns 64 queries (4 m-tiles of 16).
// Grid = B * QB * KS; split-K partials accumulated via atomicAdd.
// ---------------------------------------------------------------------------
__global__ __launch_bounds__(256, 4) void attn_kernel(
    const short* __restrict__ Qb, const short* __restrict__ Kb,
    const short* __restrict__ Vt, float* __restrict__ acc,
    float* __restrict__ lsum)
{
    __shared__ short p_lds[4][512];      // per-wave 16x32 bf16 P tile
    int tid  = threadIdx.x;
    int wave = tid >> 6, lane = tid & 63;
    int quad = lane >> 4, c15 = lane & 15;
    int blk = blockIdx.x;
    int ks = blk & (KS-1);
    int qb = (blk >> 3) & (QB-1);
    int b  = blk >> 9;
    int q_base = qb*256 + wave*64;

    const bf16x8 zero8 = (bf16x8)0;
    const f32x4  zero4 = {0.f, 0.f, 0.f, 0.f};

    // A-operand: lane holds A[m=c15][k=quad*8+j]; only k=0..7 real -> quad 0.
    bf16x8 aq[4];
    #pragma unroll
    for (int m = 0; m < 4; ++m)
        aq[m] = (quad == 0) ? ((const bf16x8*)Qb)[b*NN + q_base + m*16 + c15]
                            : zero8;

    f32x4 outf[4][2];
    float l_acc[4][4];
    #pragma unroll
    for (int m = 0; m < 4; ++m) {
        outf[m][0] = zero4; outf[m][1] = zero4;
        #pragma unroll
        for (int r = 0; r < 4; ++r) l_acc[m][r] = 0.f;
    }

    int k_base = ks*KSEG;
    short* plw = p_lds[wave];
    for (int kc = 0; kc < KSEG/32; ++kc) {
        int k0 = k_base + kc*32;
        // B-operand for scores: lane holds B[k=quad*8+j][n=c15]; quad 0 real.
        bf16x8 bk0 = (quad == 0) ? ((const bf16x8*)Kb)[b*MM + k0 + c15]      : zero8;
        bf16x8 bk1 = (quad == 0) ? ((const bf16x8*)Kb)[b*MM + k0 + 16 + c15] : zero8;
        // B-operand for PV: B[k=key=quad*8+j][n=ch=c15] from Vt rows.
        bf16x8 bv[2];
        #pragma unroll
        for (int v = 0; v < 2; ++v)
            bv[v] = *(const bf16x8*)(Vt + (b*CV + v*16 + c15)*MM + k0 + quad*8);

        #pragma unroll
        for (int m = 0; m < 4; ++m) {
            f32x4 s0 = __builtin_amdgcn_mfma_f32_16x16x32_bf16(aq[m], bk0, zero4, 0, 0, 0);
            f32x4 s1 = __builtin_amdgcn_mfma_f32_16x16x32_bf16(aq[m], bk1, zero4, 0, 0, 0);
            // C-layout: row(q_local)=quad*4+r, col(key)=c15 (+16 for chunk 1)
            #pragma unroll
            for (int r = 0; r < 4; ++r) {
                float p0 = __expf(s0[r]);
                float p1 = __expf(s1[r]);
                l_acc[m][r] += p0 + p1;
                plw[(quad*4 + r)*32 + c15]      = f2bf(p0);
                plw[(quad*4 + r)*32 + 16 + c15] = f2bf(p1);
            }
            // A-layout read back: lane holds P[q_local=c15][key=quad*8+j]
            bf16x8 ap = *(const bf16x8*)(plw + c15*32 + quad*8);
            outf[m][0] = __builtin_amdgcn_mfma_f32_16x16x32_bf16(ap, bv[0], outf[m][0], 0, 0, 0);
            outf[m][1] = __builtin_amdgcn_mfma_f32_16x16x32_bf16(ap, bv[1], outf[m][1], 0, 0, 0);
        }
    }

    // reduce row-sums l across the 16 lanes of each quad group, then atomics
    #pragma unroll
    for (int m = 0; m < 4; ++m) {
        #pragma unroll
        for (int r = 0; r < 4; ++r) {
            float v = l_acc[m][r];
            v += __shfl_xor(v, 1);
            v += __shfl_xor(v, 2);
            v += __shfl_xor(v, 4);
            v += __shfl_xor(v, 8);
            if (c15 == 0)
                atomicAdd(&lsum[b*NN + q_base + m*16 + quad*4 + r], v);
        }
    }
    #pragma unroll
    for (int m = 0; m < 4; ++m) {
        #pragma unroll
        for (int v = 0; v < 2; ++v) {
            #pragma unroll
            for (int r = 0; r < 4; ++r) {
                int q = q_base + m*16 + quad*4 + r;
                atomicAdd(&acc[(b*NN + q)*CV + v*16 + c15], outf[m][v][r]);
            }
        }
    }
}

// ---------------------------------------------------------------------------
// Kernel 3: normalize by l, apply w_o [64][32], residual + gamma.
// Block = 256 threads = 128 pixels x 2 output-channel halves. Grid = B*N/128.
// ---------------------------------------------------------------------------
__global__ __launch_bounds__(256) void epilogue_kernel(
    const float* __restrict__ x, const float* __restrict__ wo,
    const float* __restrict__ gamma, const float* __restrict__ acc,
    const float* __restrict__ lsum, float* __restrict__ out)
{
    __shared__ float wo_lds[2048];
    int tid = threadIdx.x;
    for (int i = tid; i < 2048; i += 256) wo_lds[i] = wo[i];
    __syncthreads();

    int pl = tid & 127, half = tid >> 7;
    int pix = blockIdx.x*128 + pl;          // 0 .. B*N-1
    int b = pix >> 14, n = pix & (NN - 1);

    float rl = 1.0f / lsum[pix];
    float y[32];
    const float4* av = (const float4*)(acc + (size_t)pix*CV);
    #pragma unroll
    for (int i = 0; i < 8; ++i) {
        float4 t = av[i];
        y[4*i+0] = t.x*rl; y[4*i+1] = t.y*rl;
        y[4*i+2] = t.z*rl; y[4*i+3] = t.w*rl;
    }
    float gam = gamma[0];
    #pragma unroll
    for (int j = 0; j < 32; ++j) {
        int co = half*32 + j;
        float sacc = 0.f;
        #pragma unroll
        for (int ci = 0; ci < 32; ++ci) sacc += wo_lds[co*32 + ci] * y[ci];
        int o = ((b*CC + co) << 14) + n;
        out[o] = x[o] + gam*sacc;
    }
}

// ---------------------------------------------------------------------------
// Workspace layout (bytes):
//   Qb  @ 0        : B*N*8*2  = 524288
//   Kb  @ 524288   : B*M*8*2  = 131072
//   Vt  @ 655360   : B*32*M*2 = 524288
//   acc @ 1179648  : B*N*32*4 = 4194304   (zeroed)
//   l   @ 5373952  : B*N*4    = 131072    (zeroed)
// ---------------------------------------------------------------------------
extern "C" void kernel_launch(void* const* d_in, const int* in_sizes, int n_in,
                              void* d_out, int out_size, void* d_ws, size_t ws_size,
                              hipStream_t stream) {
    const float* x     = (const float*)d_in[0];
    const float* wt    = (const float*)d_in[1];
    const float* wp    = (const float*)d_in[2];
    const float* wg    = (const float*)d_in[3];
    const float* wo    = (const float*)d_in[4];
    const float* gamma = (const float*)d_in[5];
    float* out = (float*)d_out;

    char* ws = (char*)d_ws;
    short* Qb   = (short*)(ws);
    short* Kb   = (short*)(ws + 524288);
    short* Vt   = (short*)(ws + 655360);
    float* acc  = (float*)(ws + 1179648);
    float* lsum = (float*)(ws + 5373952);

    hipMemsetAsync(ws + 1179648, 0, 4194304 + 131072, stream);

    dim3 g1(HH/2, BB);
    proj_kernel<<<g1, 256, 0, stream>>>(x, wt, wp, wg, Qb, Kb, Vt);
    attn_kernel<<<BB*QB*KS, 256, 0, stream>>>(Qb, Kb, Vt, acc, lsum);
    epilogue_kernel<<<BB*NN/128, 256, 0, stream>>>(x, wo, gamma, acc, lsum, out);
}